// Round 6
// baseline (83.628 us; speedup 1.0000x reference)
//
#include <hip/hip_runtime.h>

// DifferentiableCIndexLoss:
//   mask[i,j] = (t[i] < t[j]) && (e[i]==1)
//   loss = sum sigmoid((r[j]-r[i])/SIGMA) * mask ;  count = sum mask
//   out  = loss / (count + 1e-6)
//
// R6: TWO graph nodes total (node count dominated R3-R5 totals).
//  1) k_prep (1 block, 1024 thr): LDS histogram (1024 time buckets) of active
//     rows (e==1) and all columns -> dual scan -> chunk/page bucket bounds ->
//     scatter (2^{+s},t)/(2^{-s},t) into bucket-sorted arrays -> zero accums.
//     No cross-block sync, no memset node.
//  2) k_main (2048 blocks): block = (256-row chunk, 8 contiguous 64-wide
//     j-pages). Tile class via bucket bounds: all-false skip; all-true
//     fma+rcp+add with analytic count (no compare); mixed exact compare.
//     j-tile in registers, broadcast via __shfl (no LDS / syncs in hot loop).
//     Finalize fused: float/int atomicAdd partials + last-block-done writes
//     out = L/(C+1e-6). No spinning anywhere.
// Exactness: bucket monotone in t => bucket_i < bucket_j proves t_i < t_j;
// equal/overlapping buckets fall to exact per-pair compares. Count is exact.
//   sigmoid((r_j-r_i)/sigma) = 1/(1 + 2^{s_i} * 2^{-s_j}), s = r*log2e/sigma,
//   |s| clamped to 60 (product in [2^-120, 2^120]: no overflow/NaN).

#define NB 1024
#define PREP_T 1024
#define BLOCK 256
#define RC_SHIFT 8                 // 256 rows per chunk
#define MAXRC 64                   // 16384/256
#define JP_SHIFT 6                 // 64 cols per page
#define MAXPG 256                  // 16384/64
#define PG_PER_BLK 8
#define GRID_MAIN (MAXRC * (MAXPG / PG_PER_BLK))   // 64*32 = 2048

__device__ __forceinline__ float fast_exp2(float x) { return __builtin_amdgcn_exp2f(x); }
__device__ __forceinline__ float fast_rcp(float x)  { return __builtin_amdgcn_rcpf(x); }
__device__ __forceinline__ float clamp60(float x)   { return fminf(fmaxf(x, -60.0f), 60.0f); }
__device__ __forceinline__ int bucket_of(float tv) {
    int b = (int)(tv * (float)NB);
    return min(max(b, 0), NB - 1);
}

// ---- 1) prep: hist -> scan -> bounds -> scatter, single block ---------------
__global__ __launch_bounds__(PREP_T) void k_prep(
    const float* __restrict__ r, const float* __restrict__ t,
    const int* __restrict__ ev, int B, float kscale,
    int* __restrict__ rcLo, int* __restrict__ rcHi,
    int* __restrict__ jpLo, int* __restrict__ jpHi,
    int* __restrict__ nactive_g, float* __restrict__ Lacc,
    unsigned int* __restrict__ Cacc, unsigned int* __restrict__ done,
    float2* __restrict__ sI, float2* __restrict__ sJ) {

    __shared__ int hI[NB], hJ[NB];
    __shared__ int rcLo_s[MAXRC], rcHi_s[MAXRC];
    __shared__ int jpLo_s[MAXPG], jpHi_s[MAXPG];
    __shared__ int totI;
    const int tid = threadIdx.x;

    hI[tid] = 0; hJ[tid] = 0;
    if (tid < MAXRC) { rcLo_s[tid] = 0x7fffffff; rcHi_s[tid] = -1; }
    if (tid < MAXPG) { jpLo_s[tid] = 0x7fffffff; jpHi_s[tid] = -1; }
    __syncthreads();

    // histogram (LDS atomics)
    for (int g = tid; g < B; g += PREP_T) {
        int b = bucket_of(t[g]);
        atomicAdd(&hJ[b], 1);
        if (ev[g] == 1) atomicAdd(&hI[b], 1);
    }
    __syncthreads();

    // dual inclusive scan (Hillis-Steele, NB == PREP_T: one bucket per thread)
    const int cI = hI[tid], cJ = hJ[tid];
    for (int off = 1; off < NB; off <<= 1) {
        int vI = (tid >= off) ? hI[tid - off] : 0;
        int vJ = (tid >= off) ? hJ[tid - off] : 0;
        __syncthreads();
        hI[tid] += vI; hJ[tid] += vJ;
        __syncthreads();
    }
    const int exI = hI[tid] - cI;
    const int exJ = hJ[tid] - cJ;
    if (tid == NB - 1) totI = hI[NB - 1];

    // chunk/page bucket bounds
    if (cI > 0) {
        int c0 = exI >> RC_SHIFT, c1 = (exI + cI - 1) >> RC_SHIFT;
        for (int c = c0; c <= c1; ++c) { atomicMin(&rcLo_s[c], tid); atomicMax(&rcHi_s[c], tid); }
    }
    if (cJ > 0) {
        int c0 = exJ >> JP_SHIFT, c1 = (exJ + cJ - 1) >> JP_SHIFT;
        for (int c = c0; c <= c1; ++c) { atomicMin(&jpLo_s[c], tid); atomicMax(&jpHi_s[c], tid); }
    }
    // repurpose hist arrays as running scatter offsets
    __syncthreads();
    hI[tid] = exI; hJ[tid] = exJ;
    __syncthreads();

    // write-out bounds/ctrl (bounds atomics completed before last sync)
    if (tid < MAXRC) { rcLo[tid] = rcLo_s[tid]; rcHi[tid] = rcHi_s[tid]; }
    if (tid < MAXPG) { jpLo[tid] = jpLo_s[tid]; jpHi[tid] = jpHi_s[tid]; }
    if (tid == 0) { *nactive_g = totI; *Lacc = 0.0f; *Cacc = 0u; *done = 0u; }

    // scatter into bucket-sorted arrays
    for (int g = tid; g < B; g += PREP_T) {
        float tv = t[g];
        float s  = clamp60(r[g] * kscale);
        int b = bucket_of(tv);
        int pj = atomicAdd(&hJ[b], 1);
        sJ[pj] = make_float2(fast_exp2(-s), tv);
        if (ev[g] == 1) {
            int pi = atomicAdd(&hI[b], 1);
            sI[pi] = make_float2(fast_exp2(s), tv);
        }
    }
}

// ---- 2) main: classified tiles + fused finalize -----------------------------
__global__ __launch_bounds__(BLOCK) void k_main(
    const float2* __restrict__ sI, const float2* __restrict__ sJ,
    const int* __restrict__ rcLo, const int* __restrict__ rcHi,
    const int* __restrict__ jpLo, const int* __restrict__ jpHi,
    const int* __restrict__ nactive_g,
    float* __restrict__ Lacc, unsigned int* __restrict__ Cacc,
    unsigned int* __restrict__ done, float* __restrict__ out) {

    const int tid = threadIdx.x;
    const int rc = blockIdx.x >> 5;          // 0..63
    const int pg = blockIdx.x & 31;          // 8 contiguous pages each
    const int nactive = *nactive_g;
    const int rl = rcLo[rc], rh = rcHi[rc];
    const int lane = tid & 63;

    // my row (once per block)
    int rr = (rc << RC_SHIFT) + tid;
    int v0 = (rr < nactive) ? 1 : 0;
    float Ei = __builtin_inff(), ti = 3.0f;  // rcp(1+inf*F)=0; t<tj never fires
    if (v0) { float2 f = sI[rr]; Ei = f.x; ti = f.y; }

    float lsum = 0.0f;
    int   csum = 0;

#pragma unroll
    for (int k = 0; k < PG_PER_BLK; ++k) {
        int p = (pg << 3) + k;
        int jh = jpHi[p];
        if (rl > jh) continue;               // all-false (or empty chunk)
        int jl = jpLo[p];

        float2 q = sJ[(p << JP_SHIFT) + lane];   // one j per lane, in regs
        float Fv = q.x, tv = q.y;

        if (rh < jl) {                       // all-true: no compare
            float l = 0.0f;
#pragma unroll 8
            for (int jj = 0; jj < 64; ++jj)
                l += fast_rcp(__builtin_fmaf(Ei, __shfl(Fv, jj), 1.0f));
            lsum += l;
            csum += v0 << JP_SHIFT;          // v0 * 64
        } else {                             // mixed: exact per-pair compare
            float l = 0.0f; int c = 0;
#pragma unroll 8
            for (int jj = 0; jj < 64; ++jj) {
                float Fj = __shfl(Fv, jj);
                float tj = __shfl(tv, jj);
                float sg = fast_rcp(__builtin_fmaf(Ei, Fj, 1.0f));
                bool m = ti < tj;
                l += m ? sg : 0.0f;
                c += m;
            }
            lsum += l;
            csum += c;
        }
    }

    // block reduce
#pragma unroll
    for (int off = 32; off > 0; off >>= 1) {
        lsum += __shfl_down(lsum, off);
        csum += __shfl_down(csum, off);
    }
    __shared__ float lw[BLOCK / 64];
    __shared__ int   cw[BLOCK / 64];
    int wid = tid >> 6;
    if ((tid & 63) == 0) { lw[wid] = lsum; cw[wid] = csum; }
    __syncthreads();

    if (tid == 0) {
        float L = (lw[0] + lw[1]) + (lw[2] + lw[3]);
        int   C = (cw[0] + cw[1]) + (cw[2] + cw[3]);
        if (L != 0.0f) atomicAdd(Lacc, L);
        if (C != 0)    atomicAdd(Cacc, (unsigned)C);
        __threadfence();
        unsigned old = atomicAdd(done, 1u);
        if (old == (unsigned)(gridDim.x - 1)) {     // last block: finalize
            __threadfence();
            float Lf = __hip_atomic_load(Lacc, __ATOMIC_RELAXED, __HIP_MEMORY_SCOPE_AGENT);
            unsigned Cf = __hip_atomic_load(Cacc, __ATOMIC_RELAXED, __HIP_MEMORY_SCOPE_AGENT);
            out[0] = Lf / ((float)Cf + 1e-6f);
        }
    }
}

extern "C" void kernel_launch(void* const* d_in, const int* in_sizes, int n_in,
                              void* d_out, int out_size, void* d_ws, size_t ws_size,
                              hipStream_t stream) {
    const float* r  = (const float*)d_in[0];
    const float* t  = (const float*)d_in[1];
    const int*   ev = (const int*)d_in[2];
    float* out = (float*)d_out;
    const int B = in_sizes[0];   // 16384

    const float SIGMA = 0.1f;
    const float LOG2E = 1.4426950408889634f;
    const float kscale = LOG2E / SIGMA;

    char* ws = (char*)d_ws;
    int* rcLo = (int*)(ws + 0);
    int* rcHi = rcLo + MAXRC;
    int* jpLo = rcHi + MAXRC;
    int* jpHi = jpLo + MAXPG;
    int* nactive_g = jpHi + MAXPG;                 // @ 2560
    float* Lacc = (float*)(nactive_g + 1);
    unsigned int* Cacc = (unsigned int*)(Lacc + 1);
    unsigned int* done = Cacc + 1;
    float2* sI = (float2*)(ws + 4096);             // 128 KB
    float2* sJ = sI + B;                           // 128 KB

    k_prep<<<1, PREP_T, 0, stream>>>(r, t, ev, B, kscale,
        rcLo, rcHi, jpLo, jpHi, nactive_g, Lacc, Cacc, done, sI, sJ);
    k_main<<<GRID_MAIN, BLOCK, 0, stream>>>(sI, sJ, rcLo, rcHi, jpLo, jpHi,
        nactive_g, Lacc, Cacc, done, out);
}

// Round 7
// 77.902 us; speedup vs baseline: 1.0735x; 1.0735x over previous
//
#include <hip/hip_runtime.h>

// DifferentiableCIndexLoss:
//   mask[i,j] = (t[i] < t[j]) && (e[i]==1)
//   loss = sum sigmoid((r[j]-r[i])/SIGMA) * mask ;  count = sum mask
//   out  = loss / (count + 1e-6)
//
// R7: exact bucket-sort classification, 3 multi-block nodes, no spin/memset:
//  1) k_hist    (64 blk): per-block LDS hist of 256 elems -> store slice
//                hist[b][1024] (pure overwrite, replay-safe).
//  2) k_scatter (64 blk): each block column-sums the 64 slices (totals +
//                prefix over blocks < b), scans 1024 buckets in LDS
//                (redundant per block), scatters its 256 elems via LDS
//                cursors. Block 0 writes chunk/page bucket bounds + zeroes
//                Lacc/Cacc/done.
//  3) k_main  (2048 blk): chunk=256 rows; each WAVE holds all 256 rows
//                (4/thread) so one LDS broadcast read feeds 256 pairs.
//                8 pages (64 cols each, strided by 32 for balance) staged
//                in LDS once; waves own disjoint pages, no hot-loop syncs.
//                all-false skip / all-true fma+rcp+add + analytic count /
//                mixed exact compare. Fused finalize via done-counter.
// Exactness: bucket monotone in t => strict bucket inequality proves the
// compare; overlapping-bucket tiles use exact per-pair compares. Count exact.
//   sigmoid((r_j-r_i)/sigma) = 1/(1 + 2^{s_i} 2^{-s_j}), s=r*log2e/sigma,
//   |s|<=60 so the product is in [2^-120,2^120]: no overflow/NaN.

#define NB 1024
#define BLOCK 256
#define NBLK_DATA 64               // 16384/256
#define RC_SHIFT 8                 // 256 rows per chunk
#define MAXRC 64
#define JP_SHIFT 6                 // 64 cols per page
#define MAXPG 256
#define GRID_MAIN (MAXRC * 32)     // 2048

__device__ __forceinline__ float fast_exp2(float x) { return __builtin_amdgcn_exp2f(x); }
__device__ __forceinline__ float fast_rcp(float x)  { return __builtin_amdgcn_rcpf(x); }
__device__ __forceinline__ float clamp60(float x)   { return fminf(fmaxf(x, -60.0f), 60.0f); }
__device__ __forceinline__ int bucket_of(float tv) {
    int b = (int)(tv * (float)NB);
    return min(max(b, 0), NB - 1);
}

// ---- 1) per-block histogram slices ------------------------------------------
__global__ __launch_bounds__(BLOCK) void k_hist(
    const float* __restrict__ t, const int* __restrict__ ev,
    int* __restrict__ hIb, int* __restrict__ hJb) {
    __shared__ int hI[NB], hJ[NB];
    const int tid = threadIdx.x, b = blockIdx.x;
    for (int i = tid; i < NB; i += BLOCK) { hI[i] = 0; hJ[i] = 0; }
    __syncthreads();
    int g = (b << 8) + tid;
    int bk = bucket_of(t[g]);
    atomicAdd(&hJ[bk], 1);
    if (ev[g] == 1) atomicAdd(&hI[bk], 1);
    __syncthreads();
    int* oI = hIb + b * NB;
    int* oJ = hJb + b * NB;
    for (int i = tid; i < NB; i += BLOCK) { oI[i] = hI[i]; oJ[i] = hJ[i]; }
}

// ---- 2) scan (redundant per block) + bounds + scatter -----------------------
__global__ __launch_bounds__(BLOCK) void k_scatter(
    const float* __restrict__ r, const float* __restrict__ t,
    const int* __restrict__ ev, float kscale,
    const int* __restrict__ hIb, const int* __restrict__ hJb,
    int* __restrict__ rcLo, int* __restrict__ rcHi,
    int* __restrict__ jpLo, int* __restrict__ jpHi,
    int* __restrict__ nactive_g, float* __restrict__ Lacc,
    unsigned int* __restrict__ Cacc, unsigned int* __restrict__ done,
    float2* __restrict__ sI, float2* __restrict__ sJ) {

    const int tid = threadIdx.x, b = blockIdx.x;
    __shared__ int ps[2 * BLOCK];
    __shared__ int baseI[NB], baseJ[NB];
    __shared__ int rcLo_s[MAXRC], rcHi_s[MAXRC], jpLo_s[MAXPG], jpHi_s[MAXPG];
    const int bk0 = tid << 2;                 // 4 contiguous buckets per thread

    // column totals over 64 slices + prefix over blocks < b
    int tI[4] = {0,0,0,0}, tJ[4] = {0,0,0,0};
    int pI[4] = {0,0,0,0}, pJ[4] = {0,0,0,0};
    for (int bb = 0; bb < NBLK_DATA; ++bb) {
        int4 vI = *(const int4*)(hIb + bb * NB + bk0);
        int4 vJ = *(const int4*)(hJb + bb * NB + bk0);
        tI[0] += vI.x; tI[1] += vI.y; tI[2] += vI.z; tI[3] += vI.w;
        tJ[0] += vJ.x; tJ[1] += vJ.y; tJ[2] += vJ.z; tJ[3] += vJ.w;
        if (bb < b) {
            pI[0] += vI.x; pI[1] += vI.y; pI[2] += vI.z; pI[3] += vI.w;
            pJ[0] += vJ.x; pJ[1] += vJ.y; pJ[2] += vJ.z; pJ[3] += vJ.w;
        }
    }
    int sIt = (tI[0] + tI[1]) + (tI[2] + tI[3]);
    int sJt = (tJ[0] + tJ[1]) + (tJ[2] + tJ[3]);
    ps[tid] = sIt; ps[BLOCK + tid] = sJt;
    __syncthreads();
    for (int off = 1; off < BLOCK; off <<= 1) {       // dual Hillis-Steele
        int a = (tid >= off) ? ps[tid - off] : 0;
        int c = (tid >= off) ? ps[BLOCK + tid - off] : 0;
        __syncthreads();
        ps[tid] += a; ps[BLOCK + tid] += c;
        __syncthreads();
    }
    int exI = ps[tid] - sIt, exJ = ps[BLOCK + tid] - sJt;
    int eI[4], eJ[4];
    { int runI = exI, runJ = exJ;
#pragma unroll
      for (int k = 0; k < 4; ++k) { eI[k] = runI; runI += tI[k]; eJ[k] = runJ; runJ += tJ[k]; } }

    if (b == 0 && tid == BLOCK - 1) *nactive_g = ps[BLOCK - 1];
    if (b == 0 && tid == 0) { *Lacc = 0.0f; *Cacc = 0u; *done = 0u; }

    if (b == 0) {   // chunk/page bucket bounds (block-uniform branch: barriers legal)
        if (tid < MAXRC) { rcLo_s[tid] = 0x7fffffff; rcHi_s[tid] = -1; }
        if (tid < MAXPG) { jpLo_s[tid] = 0x7fffffff; jpHi_s[tid] = -1; }
        __syncthreads();
#pragma unroll
        for (int k = 0; k < 4; ++k) {
            int bk = bk0 + k;
            if (tI[k] > 0) {
                int c0 = eI[k] >> RC_SHIFT, c1 = (eI[k] + tI[k] - 1) >> RC_SHIFT;
                for (int c = c0; c <= c1; ++c) { atomicMin(&rcLo_s[c], bk); atomicMax(&rcHi_s[c], bk); }
            }
            if (tJ[k] > 0) {
                int c0 = eJ[k] >> JP_SHIFT, c1 = (eJ[k] + tJ[k] - 1) >> JP_SHIFT;
                for (int c = c0; c <= c1; ++c) { atomicMin(&jpLo_s[c], bk); atomicMax(&jpHi_s[c], bk); }
            }
        }
        __syncthreads();
        if (tid < MAXRC) { rcLo[tid] = rcLo_s[tid]; rcHi[tid] = rcHi_s[tid]; }
        if (tid < MAXPG) { jpLo[tid] = jpLo_s[tid]; jpHi[tid] = jpHi_s[tid]; }
    }

    // per-bucket cursors for THIS block = global excl + prefix of earlier blocks
#pragma unroll
    for (int k = 0; k < 4; ++k) {
        baseI[bk0 + k] = eI[k] + pI[k];
        baseJ[bk0 + k] = eJ[k] + pJ[k];
    }
    __syncthreads();

    // scatter my element
    int g = (b << 8) + tid;
    float tv = t[g];
    float s  = clamp60(r[g] * kscale);
    int bk = bucket_of(tv);
    int pj = atomicAdd(&baseJ[bk], 1);
    sJ[pj] = make_float2(fast_exp2(-s), tv);
    if (ev[g] == 1) {
        int pi = atomicAdd(&baseI[bk], 1);
        sI[pi] = make_float2(fast_exp2(s), tv);
    }
}

// ---- 3) main: classified tiles, wave-owns-chunk, fused finalize -------------
__global__ __launch_bounds__(BLOCK) void k_main(
    const float2* __restrict__ sI, const float2* __restrict__ sJ,
    const int* __restrict__ rcLo, const int* __restrict__ rcHi,
    const int* __restrict__ jpLo, const int* __restrict__ jpHi,
    const int* __restrict__ nactive_g,
    float* __restrict__ Lacc, unsigned int* __restrict__ Cacc,
    unsigned int* __restrict__ done, float* __restrict__ out) {

    const int tid = threadIdx.x;
    const int rc = blockIdx.x & (MAXRC - 1);
    const int psIdx = blockIdx.x >> 6;        // 0..31
    const int wid = tid >> 6, lane = tid & 63;
    const int nactive = *nactive_g;
    const int rl = rcLo[rc], rh = rcHi[rc];

    __shared__ float2 tile[8][64];            // 8 pages, strided by 32
    for (int e = tid; e < 512; e += BLOCK) {
        int m = e >> 6, jj = e & 63;
        tile[m][jj] = sJ[((psIdx + (m << 5)) << 6) + jj];
    }

    // my wave holds the whole 256-row chunk: 4 rows per lane
    float E[4], T[4];
    int nv = 0;
    const int rbase = rc << RC_SHIFT;
#pragma unroll
    for (int k = 0; k < 4; ++k) {
        int rr = rbase + lane + (k << 6);
        if (rr < nactive) { float2 f = sI[rr]; E[k] = f.x; T[k] = f.y; ++nv; }
        else              { E[k] = __builtin_inff(); T[k] = 3.0f; }  // 0 contrib
    }
    __syncthreads();

    float lsum = 0.0f;
    int   csum = 0;

#pragma unroll
    for (int mi = 0; mi < 2; ++mi) {
        int m = wid + (mi << 2);              // waves own disjoint pages
        int p = psIdx + (m << 5);
        int jh = jpHi[p];
        if (rl > jh) continue;                // all-false (or empty chunk)
        int jl = jpLo[p];

        if (rh < jl) {                        // all-true: no compare
            float l0 = 0.f, l1 = 0.f, l2 = 0.f, l3 = 0.f;
#pragma unroll 8
            for (int jj = 0; jj < 64; ++jj) {
                float F = tile[m][jj].x;      // wave-uniform LDS broadcast
                l0 += fast_rcp(__builtin_fmaf(E[0], F, 1.0f));
                l1 += fast_rcp(__builtin_fmaf(E[1], F, 1.0f));
                l2 += fast_rcp(__builtin_fmaf(E[2], F, 1.0f));
                l3 += fast_rcp(__builtin_fmaf(E[3], F, 1.0f));
            }
            lsum += (l0 + l1) + (l2 + l3);
            csum += nv << 6;                  // analytic count
        } else {                              // mixed: exact per-pair compare
            float l0 = 0.f, l1 = 0.f, l2 = 0.f, l3 = 0.f;
            int c = 0;
#pragma unroll 4
            for (int jj = 0; jj < 64; ++jj) {
                float2 q = tile[m][jj];
                float F = q.x, tj = q.y;
                float s0 = fast_rcp(__builtin_fmaf(E[0], F, 1.0f));
                float s1 = fast_rcp(__builtin_fmaf(E[1], F, 1.0f));
                float s2 = fast_rcp(__builtin_fmaf(E[2], F, 1.0f));
                float s3 = fast_rcp(__builtin_fmaf(E[3], F, 1.0f));
                bool m0 = T[0] < tj, m1 = T[1] < tj, m2 = T[2] < tj, m3 = T[3] < tj;
                l0 += m0 ? s0 : 0.0f; c += m0;
                l1 += m1 ? s1 : 0.0f; c += m1;
                l2 += m2 ? s2 : 0.0f; c += m2;
                l3 += m3 ? s3 : 0.0f; c += m3;
            }
            lsum += (l0 + l1) + (l2 + l3);
            csum += c;
        }
    }

    // block reduce + fused finalize (R6-proven pattern)
#pragma unroll
    for (int off = 32; off > 0; off >>= 1) {
        lsum += __shfl_down(lsum, off);
        csum += __shfl_down(csum, off);
    }
    __shared__ float lw[BLOCK / 64];
    __shared__ int   cw[BLOCK / 64];
    if ((tid & 63) == 0) { lw[wid] = lsum; cw[wid] = csum; }
    __syncthreads();
    if (tid == 0) {
        float L = (lw[0] + lw[1]) + (lw[2] + lw[3]);
        int   C = (cw[0] + cw[1]) + (cw[2] + cw[3]);
        if (L != 0.0f) atomicAdd(Lacc, L);
        if (C != 0)    atomicAdd(Cacc, (unsigned)C);
        __threadfence();
        unsigned old = atomicAdd(done, 1u);
        if (old == (unsigned)(gridDim.x - 1)) {
            __threadfence();
            float Lf = __hip_atomic_load(Lacc, __ATOMIC_RELAXED, __HIP_MEMORY_SCOPE_AGENT);
            unsigned Cf = __hip_atomic_load(Cacc, __ATOMIC_RELAXED, __HIP_MEMORY_SCOPE_AGENT);
            out[0] = Lf / ((float)Cf + 1e-6f);
        }
    }
}

extern "C" void kernel_launch(void* const* d_in, const int* in_sizes, int n_in,
                              void* d_out, int out_size, void* d_ws, size_t ws_size,
                              hipStream_t stream) {
    const float* r  = (const float*)d_in[0];
    const float* t  = (const float*)d_in[1];
    const int*   ev = (const int*)d_in[2];
    float* out = (float*)d_out;
    const int B = in_sizes[0];   // 16384

    const float SIGMA = 0.1f;
    const float LOG2E = 1.4426950408889634f;
    const float kscale = LOG2E / SIGMA;

    char* ws = (char*)d_ws;
    int* rcLo = (int*)(ws + 0);          // 64
    int* rcHi = (int*)(ws + 256);        // 64
    int* jpLo = (int*)(ws + 512);        // 256
    int* jpHi = (int*)(ws + 1536);       // 256
    int* nactive_g      = (int*)(ws + 2560);
    float* Lacc         = (float*)(ws + 2564);
    unsigned int* Cacc  = (unsigned int*)(ws + 2568);
    unsigned int* done  = (unsigned int*)(ws + 2572);
    int* hIb   = (int*)(ws + 4096);                       // 64*1024*4 = 256 KB
    int* hJb   = (int*)(ws + 4096 + 262144);              // 256 KB
    float2* sI = (float2*)(ws + 4096 + 524288);           // 128 KB
    float2* sJ = (float2*)(ws + 4096 + 524288 + 131072);  // 128 KB

    k_hist<<<NBLK_DATA, BLOCK, 0, stream>>>(t, ev, hIb, hJb);
    k_scatter<<<NBLK_DATA, BLOCK, 0, stream>>>(r, t, ev, kscale, hIb, hJb,
        rcLo, rcHi, jpLo, jpHi, nactive_g, Lacc, Cacc, done, sI, sJ);
    k_main<<<GRID_MAIN, BLOCK, 0, stream>>>(sI, sJ, rcLo, rcHi, jpLo, jpHi,
        nactive_g, Lacc, Cacc, done, out);
}

// Round 8
// 56.779 us; speedup vs baseline: 1.4729x; 1.3720x over previous
//
#include <hip/hip_runtime.h>

// DifferentiableCIndexLoss:
//   mask[i,j] = (t[i] < t[j]) && (e[i]==1)
//   loss = sum sigmoid((r[j]-r[i])/SIGMA) * mask ;  count = sum mask
//   out  = loss / (count + 1e-6)
//
// R8 = R7 with ONE change: fused device-scope-atomic finalize REMOVED.
// R7's k_main was 55.6us at VALUBusy 12% -- the per-block atomicAdd
// (same-address, cross-XCD) + __threadfence() tail dominated; the VALU work
// itself was ~7us. Blocks now store partials (plain coalesced stores) and a
// 4th tiny node reduces them in double. (R4/R5/R6/R7 lesson: NO device-scope
// fences/atomics/spins anywhere.)
//
// Pipeline:
//  1) k_hist    (64 blk): per-block LDS hist slices (pure overwrite).
//  2) k_scatter (64 blk): redundant column-sum+scan per block -> scatter via
//                LDS cursors; block 0 writes chunk/page bucket bounds.
//  3) k_main  (2048 blk): chunk=256 rows; each WAVE holds all 256 rows
//                (4/lane); 8 pages staged in LDS; waves own disjoint pages.
//                all-false skip / all-true fma+rcp+add + analytic count /
//                mixed exact compare. Partials -> pL/pC (plain stores).
//  4) k_finalize (1 blk): double-precision reduce, out = L/(C+1e-6).
// Exactness: bucket monotone in t => strict bucket inequality proves the
// compare; overlapping-bucket tiles use exact per-pair compares. Count exact.
//   sigmoid((r_j-r_i)/sigma) = 1/(1 + 2^{s_i} 2^{-s_j}), s=r*log2e/sigma,
//   |s|<=60 so the product is in [2^-120,2^120]: no overflow/NaN.

#define NB 1024
#define BLOCK 256
#define NBLK_DATA 64               // 16384/256
#define RC_SHIFT 8                 // 256 rows per chunk
#define MAXRC 64
#define JP_SHIFT 6                 // 64 cols per page
#define MAXPG 256
#define GRID_MAIN (MAXRC * 32)     // 2048

__device__ __forceinline__ float fast_exp2(float x) { return __builtin_amdgcn_exp2f(x); }
__device__ __forceinline__ float fast_rcp(float x)  { return __builtin_amdgcn_rcpf(x); }
__device__ __forceinline__ float clamp60(float x)   { return fminf(fmaxf(x, -60.0f), 60.0f); }
__device__ __forceinline__ int bucket_of(float tv) {
    int b = (int)(tv * (float)NB);
    return min(max(b, 0), NB - 1);
}

// ---- 1) per-block histogram slices ------------------------------------------
__global__ __launch_bounds__(BLOCK) void k_hist(
    const float* __restrict__ t, const int* __restrict__ ev,
    int* __restrict__ hIb, int* __restrict__ hJb) {
    __shared__ int hI[NB], hJ[NB];
    const int tid = threadIdx.x, b = blockIdx.x;
    for (int i = tid; i < NB; i += BLOCK) { hI[i] = 0; hJ[i] = 0; }
    __syncthreads();
    int g = (b << 8) + tid;
    int bk = bucket_of(t[g]);
    atomicAdd(&hJ[bk], 1);
    if (ev[g] == 1) atomicAdd(&hI[bk], 1);
    __syncthreads();
    int* oI = hIb + b * NB;
    int* oJ = hJb + b * NB;
    for (int i = tid; i < NB; i += BLOCK) { oI[i] = hI[i]; oJ[i] = hJ[i]; }
}

// ---- 2) scan (redundant per block) + bounds + scatter -----------------------
__global__ __launch_bounds__(BLOCK) void k_scatter(
    const float* __restrict__ r, const float* __restrict__ t,
    const int* __restrict__ ev, float kscale,
    const int* __restrict__ hIb, const int* __restrict__ hJb,
    int* __restrict__ rcLo, int* __restrict__ rcHi,
    int* __restrict__ jpLo, int* __restrict__ jpHi,
    int* __restrict__ nactive_g,
    float2* __restrict__ sI, float2* __restrict__ sJ) {

    const int tid = threadIdx.x, b = blockIdx.x;
    __shared__ int ps[2 * BLOCK];
    __shared__ int baseI[NB], baseJ[NB];
    __shared__ int rcLo_s[MAXRC], rcHi_s[MAXRC], jpLo_s[MAXPG], jpHi_s[MAXPG];
    const int bk0 = tid << 2;                 // 4 contiguous buckets per thread

    // column totals over 64 slices + prefix over blocks < b
    int tI[4] = {0,0,0,0}, tJ[4] = {0,0,0,0};
    int pI[4] = {0,0,0,0}, pJ[4] = {0,0,0,0};
    for (int bb = 0; bb < NBLK_DATA; ++bb) {
        int4 vI = *(const int4*)(hIb + bb * NB + bk0);
        int4 vJ = *(const int4*)(hJb + bb * NB + bk0);
        tI[0] += vI.x; tI[1] += vI.y; tI[2] += vI.z; tI[3] += vI.w;
        tJ[0] += vJ.x; tJ[1] += vJ.y; tJ[2] += vJ.z; tJ[3] += vJ.w;
        if (bb < b) {
            pI[0] += vI.x; pI[1] += vI.y; pI[2] += vI.z; pI[3] += vI.w;
            pJ[0] += vJ.x; pJ[1] += vJ.y; pJ[2] += vJ.z; pJ[3] += vJ.w;
        }
    }
    int sIt = (tI[0] + tI[1]) + (tI[2] + tI[3]);
    int sJt = (tJ[0] + tJ[1]) + (tJ[2] + tJ[3]);
    ps[tid] = sIt; ps[BLOCK + tid] = sJt;
    __syncthreads();
    for (int off = 1; off < BLOCK; off <<= 1) {       // dual Hillis-Steele
        int a = (tid >= off) ? ps[tid - off] : 0;
        int c = (tid >= off) ? ps[BLOCK + tid - off] : 0;
        __syncthreads();
        ps[tid] += a; ps[BLOCK + tid] += c;
        __syncthreads();
    }
    int exI = ps[tid] - sIt, exJ = ps[BLOCK + tid] - sJt;
    int eI[4], eJ[4];
    { int runI = exI, runJ = exJ;
#pragma unroll
      for (int k = 0; k < 4; ++k) { eI[k] = runI; runI += tI[k]; eJ[k] = runJ; runJ += tJ[k]; } }

    if (b == 0 && tid == BLOCK - 1) *nactive_g = ps[BLOCK - 1];

    if (b == 0) {   // chunk/page bucket bounds (block-uniform branch)
        if (tid < MAXRC) { rcLo_s[tid] = 0x7fffffff; rcHi_s[tid] = -1; }
        if (tid < MAXPG) { jpLo_s[tid] = 0x7fffffff; jpHi_s[tid] = -1; }
        __syncthreads();
#pragma unroll
        for (int k = 0; k < 4; ++k) {
            int bk = bk0 + k;
            if (tI[k] > 0) {
                int c0 = eI[k] >> RC_SHIFT, c1 = (eI[k] + tI[k] - 1) >> RC_SHIFT;
                for (int c = c0; c <= c1; ++c) { atomicMin(&rcLo_s[c], bk); atomicMax(&rcHi_s[c], bk); }
            }
            if (tJ[k] > 0) {
                int c0 = eJ[k] >> JP_SHIFT, c1 = (eJ[k] + tJ[k] - 1) >> JP_SHIFT;
                for (int c = c0; c <= c1; ++c) { atomicMin(&jpLo_s[c], bk); atomicMax(&jpHi_s[c], bk); }
            }
        }
        __syncthreads();
        if (tid < MAXRC) { rcLo[tid] = rcLo_s[tid]; rcHi[tid] = rcHi_s[tid]; }
        if (tid < MAXPG) { jpLo[tid] = jpLo_s[tid]; jpHi[tid] = jpHi_s[tid]; }
    }

    // per-bucket cursors for THIS block = global excl + prefix of earlier blocks
#pragma unroll
    for (int k = 0; k < 4; ++k) {
        baseI[bk0 + k] = eI[k] + pI[k];
        baseJ[bk0 + k] = eJ[k] + pJ[k];
    }
    __syncthreads();

    // scatter my element
    int g = (b << 8) + tid;
    float tv = t[g];
    float s  = clamp60(r[g] * kscale);
    int bk = bucket_of(tv);
    int pj = atomicAdd(&baseJ[bk], 1);
    sJ[pj] = make_float2(fast_exp2(-s), tv);
    if (ev[g] == 1) {
        int pi = atomicAdd(&baseI[bk], 1);
        sI[pi] = make_float2(fast_exp2(s), tv);
    }
}

// ---- 3) main: classified tiles, wave-owns-chunk, plain partial stores -------
__global__ __launch_bounds__(BLOCK) void k_main(
    const float2* __restrict__ sI, const float2* __restrict__ sJ,
    const int* __restrict__ rcLo, const int* __restrict__ rcHi,
    const int* __restrict__ jpLo, const int* __restrict__ jpHi,
    const int* __restrict__ nactive_g,
    float* __restrict__ pL, unsigned int* __restrict__ pC) {

    const int tid = threadIdx.x;
    const int rc = blockIdx.x & (MAXRC - 1);
    const int psIdx = blockIdx.x >> 6;        // 0..31
    const int wid = tid >> 6, lane = tid & 63;
    const int nactive = *nactive_g;
    const int rl = rcLo[rc], rh = rcHi[rc];

    __shared__ float2 tile[8][64];            // 8 pages, strided by 32
    for (int e = tid; e < 512; e += BLOCK) {
        int m = e >> 6, jj = e & 63;
        tile[m][jj] = sJ[((psIdx + (m << 5)) << 6) + jj];
    }

    // my wave holds the whole 256-row chunk: 4 rows per lane
    float E[4], T[4];
    int nv = 0;
    const int rbase = rc << RC_SHIFT;
#pragma unroll
    for (int k = 0; k < 4; ++k) {
        int rr = rbase + lane + (k << 6);
        if (rr < nactive) { float2 f = sI[rr]; E[k] = f.x; T[k] = f.y; ++nv; }
        else              { E[k] = __builtin_inff(); T[k] = 3.0f; }  // 0 contrib
    }
    __syncthreads();

    float lsum = 0.0f;
    int   csum = 0;

#pragma unroll
    for (int mi = 0; mi < 2; ++mi) {
        int m = wid + (mi << 2);              // waves own disjoint pages
        int p = psIdx + (m << 5);
        int jh = jpHi[p];
        if (rl > jh) continue;                // all-false (or empty chunk)
        int jl = jpLo[p];

        if (rh < jl) {                        // all-true: no compare
            float l0 = 0.f, l1 = 0.f, l2 = 0.f, l3 = 0.f;
#pragma unroll 8
            for (int jj = 0; jj < 64; ++jj) {
                float F = tile[m][jj].x;      // wave-uniform LDS broadcast
                l0 += fast_rcp(__builtin_fmaf(E[0], F, 1.0f));
                l1 += fast_rcp(__builtin_fmaf(E[1], F, 1.0f));
                l2 += fast_rcp(__builtin_fmaf(E[2], F, 1.0f));
                l3 += fast_rcp(__builtin_fmaf(E[3], F, 1.0f));
            }
            lsum += (l0 + l1) + (l2 + l3);
            csum += nv << 6;                  // analytic count
        } else {                              // mixed: exact per-pair compare
            float l0 = 0.f, l1 = 0.f, l2 = 0.f, l3 = 0.f;
            int c = 0;
#pragma unroll 4
            for (int jj = 0; jj < 64; ++jj) {
                float2 q = tile[m][jj];
                float F = q.x, tj = q.y;
                float s0 = fast_rcp(__builtin_fmaf(E[0], F, 1.0f));
                float s1 = fast_rcp(__builtin_fmaf(E[1], F, 1.0f));
                float s2 = fast_rcp(__builtin_fmaf(E[2], F, 1.0f));
                float s3 = fast_rcp(__builtin_fmaf(E[3], F, 1.0f));
                bool m0 = T[0] < tj, m1 = T[1] < tj, m2 = T[2] < tj, m3 = T[3] < tj;
                l0 += m0 ? s0 : 0.0f; c += m0;
                l1 += m1 ? s1 : 0.0f; c += m1;
                l2 += m2 ? s2 : 0.0f; c += m2;
                l3 += m3 ? s3 : 0.0f; c += m3;
            }
            lsum += (l0 + l1) + (l2 + l3);
            csum += c;
        }
    }

    // block reduce + PLAIN partial stores (no device-scope atomics/fences)
#pragma unroll
    for (int off = 32; off > 0; off >>= 1) {
        lsum += __shfl_down(lsum, off);
        csum += __shfl_down(csum, off);
    }
    __shared__ float lw[BLOCK / 64];
    __shared__ int   cw[BLOCK / 64];
    if ((tid & 63) == 0) { lw[wid] = lsum; cw[wid] = csum; }
    __syncthreads();
    if (tid == 0) {
        pL[blockIdx.x] = (lw[0] + lw[1]) + (lw[2] + lw[3]);
        pC[blockIdx.x] = (unsigned)((cw[0] + cw[1]) + (cw[2] + cw[3]));
    }
}

// ---- 4) finalize --------------------------------------------------------------
__global__ __launch_bounds__(BLOCK) void k_finalize(
    const float* __restrict__ pL, const unsigned int* __restrict__ pC,
    int n, float* __restrict__ out) {
    double l = 0.0, c = 0.0;
    for (int i = threadIdx.x; i < n; i += BLOCK) {
        l += (double)pL[i];
        c += (double)pC[i];
    }
#pragma unroll
    for (int off = 32; off > 0; off >>= 1) {
        l += __shfl_down(l, off);
        c += __shfl_down(c, off);
    }
    __shared__ double lw[BLOCK / 64], cw[BLOCK / 64];
    int wid = threadIdx.x >> 6;
    if ((threadIdx.x & 63) == 0) { lw[wid] = l; cw[wid] = c; }
    __syncthreads();
    if (threadIdx.x == 0) {
        double L = (lw[0] + lw[1]) + (lw[2] + lw[3]);
        double C = (cw[0] + cw[1]) + (cw[2] + cw[3]);
        out[0] = (float)(L / (C + 1e-6));
    }
}

extern "C" void kernel_launch(void* const* d_in, const int* in_sizes, int n_in,
                              void* d_out, int out_size, void* d_ws, size_t ws_size,
                              hipStream_t stream) {
    const float* r  = (const float*)d_in[0];
    const float* t  = (const float*)d_in[1];
    const int*   ev = (const int*)d_in[2];
    float* out = (float*)d_out;
    const int B = in_sizes[0];   // 16384

    const float SIGMA = 0.1f;
    const float LOG2E = 1.4426950408889634f;
    const float kscale = LOG2E / SIGMA;

    char* ws = (char*)d_ws;
    int* rcLo = (int*)(ws + 0);          // 64 ints
    int* rcHi = (int*)(ws + 256);        // 64 ints
    int* jpLo = (int*)(ws + 512);        // 256 ints
    int* jpHi = (int*)(ws + 1536);       // 256 ints
    int* nactive_g = (int*)(ws + 2560);
    int* hIb   = (int*)(ws + 4096);                       // 64*1024*4 = 256 KB
    int* hJb   = (int*)(ws + 4096 + 262144);              // 256 KB
    float2* sI = (float2*)(ws + 4096 + 524288);           // 128 KB
    float2* sJ = (float2*)(ws + 4096 + 524288 + 131072);  // 128 KB
    float*  pL = (float*)(ws + 4096 + 524288 + 262144);
    unsigned int* pC = (unsigned int*)((char*)pL + (size_t)GRID_MAIN * 4);

    k_hist<<<NBLK_DATA, BLOCK, 0, stream>>>(t, ev, hIb, hJb);
    k_scatter<<<NBLK_DATA, BLOCK, 0, stream>>>(r, t, ev, kscale, hIb, hJb,
        rcLo, rcHi, jpLo, jpHi, nactive_g, sI, sJ);
    k_main<<<GRID_MAIN, BLOCK, 0, stream>>>(sI, sJ, rcLo, rcHi, jpLo, jpHi,
        nactive_g, pL, pC);
    k_finalize<<<1, BLOCK, 0, stream>>>(pL, pC, GRID_MAIN, out);
}